// Round 2
// baseline (256.389 us; speedup 1.0000x reference)
//
#include <hip/hip_runtime.h>
#include <stdint.h>

#define OUT_H 8
#define MAX_W 384
#define MAX_ROI 10
#define FH 160
#define FW 160
#define FC 256

#define JPB 16                        // j-columns per block (4 per wave)
#define JT (MAX_W / JPB)              // 24 j-tiles per (roi, i) row
#define NBLK (MAX_ROI * OUT_H * JT)   // 1920 blocks; 1920 % 8 == 0 (bijective swizzle)

typedef float v4f __attribute__((ext_vector_type(4)));   // clang vector: valid for nontemporal builtins

__global__ __launch_bounds__(256) void roi_warp_kernel(
    const float* __restrict__ fm,      // [8,160,160,256] f32
    const float* __restrict__ theta,   // [10,6] f32
    const int* __restrict__ masks,     // [10]
    const int* __restrict__ widths,    // [10]
    float* __restrict__ out)           // [10,8,384,256] f32
{
    const int tx   = threadIdx.x;
    const int lane = tx & 63;          // channel group within wave
    const int wg   = tx >> 6;          // 0..3: which 4-col strip of the 16-col tile
    const int c    = lane << 2;        // channel 0..252, float4 per lane => 1KB/wave

    // XCD-contiguous swizzle: blockIdx%8 = XCD (heuristic); give each XCD a
    // CONTIGUOUS 240-block chunk of roi-major work so j/i-neighboring tiles
    // (which share bilinear pixels) reuse the same per-XCD L2.
    const int bid = blockIdx.x;
    const int wid = (bid & 7) * (NBLK / 8) + (bid >> 3);
    const int roi = wid / (OUT_H * JT);
    const int rem = wid - roi * (OUT_H * JT);
    const int i   = rem / JT;
    const int jt  = rem - i * JT;

    const int j0 = jt * JPB + wg * 4;  // first of this thread's 4 consecutive j

    const int w = widths[roi];
    float* outp = out + ((((size_t)roi * OUT_H + i) * MAX_W + j0) * FC + c);

    if (j0 >= w) {
        // whole 4-column strip is padding: stream zeros, bypass L2
        const v4f z = (v4f){0.f, 0.f, 0.f, 0.f};
        #pragma unroll
        for (int u = 0; u < 4; ++u)
            __builtin_nontemporal_store(z, reinterpret_cast<v4f*>(outp + (size_t)u * FC));
        return;
    }

    const int bidx = masks[roi];
    const float* tp = theta + roi * 6;
    const float t00 = tp[0], t01 = tp[1], t02 = tp[2];
    const float t10 = tp[3], t11 = tp[4], t12 = tp[5];

    const int wm1 = (w - 1) > 1 ? (w - 1) : 1;
    const float rd2 = 2.0f / (float)wm1;                 // x_t = -1 + j*(2/(w-1))
    const float y_t = -1.0f + 2.0f * (float)i / 7.0f;    // linspace(-1,1,8)[i]
    const float xs_y = t01 * y_t + t02;                  // hoisted y-dependent terms
    const float ys_y = t11 * y_t + t12;

    const float* plane = fm + (size_t)bidx * ((size_t)FH * FW * FC) + c;

    // 4 independent bilinear samples per thread -> 16 global loads in flight
    #pragma unroll
    for (int u = 0; u < 4; ++u) {
        const int j = j0 + u;
        v4f R = (v4f){0.f, 0.f, 0.f, 0.f};
        if (j < w) {   // wave-uniform (j depends only on wg,u)
            const float x_t = fmaf((float)j, rd2, -1.0f);
            const float x = (fmaf(t00, x_t, xs_y) + 1.0f) * ((float)FW * 0.5f);
            const float y = (fmaf(t10, x_t, ys_y) + 1.0f) * ((float)FH * 0.5f);

            const float x0f = floorf(x);
            const float y0f = floorf(y);
            int x0 = (int)x0f, y0 = (int)y0f;
            int x1 = x0 + 1,   y1 = y0 + 1;
            x0 = min(max(x0, 0), FW - 1);
            x1 = min(max(x1, 0), FW - 1);
            y0 = min(max(y0, 0), FH - 1);
            y1 = min(max(y1, 0), FH - 1);

            // weights from UNCLIPPED floor values (reference convention)
            const float gx0 = (x0f + 1.0f) - x;
            const float gx1 = x - x0f;
            const float gy0 = (y0f + 1.0f) - y;
            const float gy1 = y - y0f;
            const float wa = gx0 * gy0;   // [y0,x0]
            const float wb = gx0 * gy1;   // [y1,x0]
            const float wc = gx1 * gy0;   // [y0,x1]
            const float wd = gx1 * gy1;   // [y1,x1]

            const v4f A  = *reinterpret_cast<const v4f*>(plane + ((size_t)y0 * FW + x0) * FC);
            const v4f Bv = *reinterpret_cast<const v4f*>(plane + ((size_t)y1 * FW + x0) * FC);
            const v4f Cv = *reinterpret_cast<const v4f*>(plane + ((size_t)y0 * FW + x1) * FC);
            const v4f Dv = *reinterpret_cast<const v4f*>(plane + ((size_t)y1 * FW + x1) * FC);

            R = wa * A + wb * Bv + wc * Cv + wd * Dv;
        }
        // output has zero reuse: stream past L2 so fm lines stay cached
        __builtin_nontemporal_store(R, reinterpret_cast<v4f*>(outp + (size_t)u * FC));
    }
}

extern "C" void kernel_launch(void* const* d_in, const int* in_sizes, int n_in,
                              void* d_out, int out_size, void* d_ws, size_t ws_size,
                              hipStream_t stream) {
    const float* fm     = (const float*)d_in[0];
    const float* theta  = (const float*)d_in[1];
    const int*   masks  = (const int*)d_in[2];
    const int*   widths = (const int*)d_in[3];
    float*       out    = (float*)d_out;

    roi_warp_kernel<<<NBLK, 256, 0, stream>>>(fm, theta, masks, widths, out);
}